// Round 13
// baseline (180.930 us; speedup 1.0000x reference)
//
#include <hip/hip_runtime.h>

// N=8192, D=16 RBF transport loss — all-MFMA, no-LDS (R8 structure).
// P^T via operand-swapped 16x16x16 MFMA; C/D layout == A-operand layout, so
// exp(P^T) feeds the second MFMA directly. RBF bias rides in the MFMA C
// operand (must stay pre-exp: removing it overflows fp16); exp() is raw
// v_exp_f32 via sqrt(log2e) pre-scaling.
// R13 deltas vs R12: fp16 Upart (half the partial-U traffic); k_final fused
// into pass2 via last-block counter.
#define NPTS 8192
#define DIM  16

constexpr int BLK = 256;
constexpr int NIB = NPTS / BLK;   // 32

#define REG_LAMBDA 0.01f
#define C1 1.2011224087864498f   // sqrt(log2e)      -> exp(-d2/2)
#define C2 0.6005612043932249f   // 0.5*sqrt(log2e)  -> exp(-d2/8)

typedef _Float16 h4 __attribute__((ext_vector_type(4)));
typedef float    f4 __attribute__((ext_vector_type(4)));

#define MFMA16(a, b, c) __builtin_amdgcn_mfma_f32_16x16x16f16((a), (b), (c), 0, 0, 0)

#if __has_builtin(__builtin_amdgcn_exp2f)
#define EXP2(x) __builtin_amdgcn_exp2f(x)
#else
#define EXP2(x) exp2f(x)
#endif

__device__ __forceinline__ float dot4(float4 a, float4 b) {
  return fmaf(a.x, b.x, fmaf(a.y, b.y, fmaf(a.z, b.z, a.w * b.w)));
}

__device__ __forceinline__ float block_sum(float v, float* wbuf) {
#pragma unroll
  for (int o = 32; o > 0; o >>= 1) v += __shfl_down(v, o, 64);
  const int lane = threadIdx.x & 63;
  const int wid  = threadIdx.x >> 6;
  __syncthreads();
  if (lane == 0) wbuf[wid] = v;
  __syncthreads();
  float s = 0.f;
  if (threadIdx.x == 0) {
#pragma unroll
    for (int w = 0; w < BLK / 64; ++w) s += wbuf[w];
  }
  return s;
}

// Prep: two pre-scaled fp16 X copies, LamT (16 x N, fp16), csq from ROUNDED X.
// Zeroes accums[0..3] (accums[2] is pass2's completion counter).
__global__ __launch_bounds__(BLK) void k_prep(
    const float4* __restrict__ Xv, const float4* __restrict__ Lv,
    _Float16* __restrict__ Xh1, _Float16* __restrict__ Xh2,
    _Float16* __restrict__ LamT,
    float* __restrict__ csq1, float* __restrict__ csq2,
    float* __restrict__ accums) {
  if (blockIdx.x == 0 && threadIdx.x < 4) accums[threadIdx.x] = 0.f;
  const int i = blockIdx.x * BLK + threadIdx.x;
  float sq1 = 0.f, sq2 = 0.f;
  h4* x1 = (h4*)(Xh1 + (size_t)i * DIM);
  h4* x2 = (h4*)(Xh2 + (size_t)i * DIM);
#pragma unroll
  for (int q = 0; q < 4; ++q) {
    const float4 v = Xv[(size_t)i * 4 + q];
    h4 a = {(_Float16)(C1 * v.x), (_Float16)(C1 * v.y),
            (_Float16)(C1 * v.z), (_Float16)(C1 * v.w)};
    h4 b = {(_Float16)(C2 * v.x), (_Float16)(C2 * v.y),
            (_Float16)(C2 * v.z), (_Float16)(C2 * v.w)};
    x1[q] = a; x2[q] = b;
#pragma unroll
    for (int t = 0; t < 4; ++t) {
      const float fa = (float)a[t], fb = (float)b[t];
      sq1 = fmaf(fa, fa, sq1);
      sq2 = fmaf(fb, fb, sq2);
    }
    const float4 l = Lv[(size_t)i * 4 + q];
    LamT[(size_t)(4 * q + 0) * NPTS + i] = (_Float16)l.x;
    LamT[(size_t)(4 * q + 1) * NPTS + i] = (_Float16)l.y;
    LamT[(size_t)(4 * q + 2) * NPTS + i] = (_Float16)l.z;
    LamT[(size_t)(4 * q + 3) * NPTS + i] = (_Float16)l.w;
  }
  csq1[i] = -0.5f * sq1;
  csq2[i] = -0.5f * sq2;
}

// Pass 1 (R8): U = exp2(Xj.Xi^T + bias) @ Lam. 4 i-tiles per wave,
// 256 i per block, grid (32, 32). Partials stored fp16.
__global__ __launch_bounds__(BLK) void k_pass1(
    const _Float16* __restrict__ Xh1, const _Float16* __restrict__ LamT,
    const float* __restrict__ csq1, _Float16* __restrict__ Upart, int span) {
  const int lane = threadIdx.x & 63;
  const int w    = threadIdx.x >> 6;
  const int l16  = lane & 15;
  const int quad = lane >> 4;

  const int i0 = blockIdx.x * 256 + w * 64;   // tiles i0+16t, t=0..3
  h4 bxi[4];
  float ci[4];
#pragma unroll
  for (int t = 0; t < 4; ++t) {
    bxi[t] = *(const h4*)(Xh1 + (size_t)(i0 + 16 * t + l16) * DIM + quad * 4);
    ci[t]  = csq1[i0 + 16 * t + l16];
  }
  const _Float16* blrow = LamT + (size_t)l16 * NPTS;

  f4 U[4] = {{0.f, 0.f, 0.f, 0.f}, {0.f, 0.f, 0.f, 0.f},
             {0.f, 0.f, 0.f, 0.f}, {0.f, 0.f, 0.f, 0.f}};
  const int jbeg = blockIdx.y * span;
  const int jend = jbeg + span;
#pragma unroll 4
  for (int j0 = jbeg; j0 < jend; j0 += 16) {
    const h4 axj = *(const h4*)(Xh1 + (size_t)(j0 + l16) * DIM + quad * 4);
    const float4 cjf = *(const float4*)(csq1 + j0 + quad * 4);
    const h4 bl = *(const h4*)(blrow + j0 + quad * 4);
#pragma unroll
    for (int t = 0; t < 4; ++t) {
      const f4 cc = {cjf.x + ci[t], cjf.y + ci[t], cjf.z + ci[t], cjf.w + ci[t]};
      const f4 p = MFMA16(axj, bxi[t], cc);   // P^T tile t (+bias)
      h4 ap;
#pragma unroll
      for (int r = 0; r < 4; ++r) ap[r] = (_Float16)EXP2(p[r]);
      U[t] = MFMA16(ap, bl, U[t]);
    }
  }

  _Float16* dst = Upart + ((size_t)blockIdx.y * NPTS + i0) * DIM;
#pragma unroll
  for (int t = 0; t < 4; ++t)
#pragma unroll
    for (int r = 0; r < 4; ++r)
      dst[(16 * t + quad * 4 + r) * DIM + l16] = (_Float16)U[t][r];
}

// Reduce fp16 partials -> diff = U - Y (fp16 Dh); reg = sum(Lam * U).
__global__ __launch_bounds__(BLK) void k_reduce(
    const _Float16* __restrict__ Upart, const float4* __restrict__ Yv,
    const float4* __restrict__ Lv, _Float16* __restrict__ Dh,
    float* __restrict__ accums, int jc) {
  __shared__ float wred[BLK / 64];
  const int t = blockIdx.x * BLK + threadIdx.x;
  const int i = t >> 2, q = t & 3;
  float4 u = {0.f, 0.f, 0.f, 0.f};
  for (int c = 0; c < jc; ++c) {
    const h4 p = *(const h4*)(Upart + ((size_t)c * NPTS + i) * DIM + q * 4);
    u.x += (float)p[0]; u.y += (float)p[1];
    u.z += (float)p[2]; u.w += (float)p[3];
  }
  const float4 y = Yv[(size_t)i * 4 + q];
  h4 d = {(_Float16)(u.x - y.x), (_Float16)(u.y - y.y),
          (_Float16)(u.z - y.z), (_Float16)(u.w - y.w)};
  *(h4*)(Dh + (size_t)i * DIM + q * 4) = d;
  const float regp = dot4(Lv[(size_t)i * 4 + q], u);
  const float rtot = block_sum(regp, wred);
  if (threadIdx.x == 0) unsafeAtomicAdd(&accums[1], rtot);
}

// Pass 2, symmetric wrapped-triangle map + fused final (last-block pattern).
// bi over 32 i-blocks (256 i, 4 tiles/wave); k = blockIdx.y>>1,
// half = blockIdx.y&1; bj = (bi+k)&31, j-half-span 128. k=0 weight 1, else 2;
// k==16 only bi<16. ALL blocks increment the completion counter.
__global__ __launch_bounds__(BLK) void k_pass2(
    const _Float16* __restrict__ Xh2, const _Float16* __restrict__ Dh,
    const float* __restrict__ csq2, float* __restrict__ accums,
    float* __restrict__ out) {
  __shared__ float wred[BLK / 64];
  const int bi   = blockIdx.x;
  const int k    = blockIdx.y >> 1;
  const int half = blockIdx.y & 1;
  const bool active = !(k == 16 && bi >= 16);

  if (active) {
    const int bj = (bi + k) & 31;
    const float weight = (k == 0) ? 1.f : 2.f;
    const int lane = threadIdx.x & 63;
    const int w    = threadIdx.x >> 6;
    const int l16  = lane & 15;
    const int quad = lane >> 4;
    const f4 fz = {0.f, 0.f, 0.f, 0.f};

    const int i0 = bi * 256 + w * 64;
    h4 ax[4], ad[4];
    float4 cif[4];
#pragma unroll
    for (int t = 0; t < 4; ++t) {
      ax[t] = *(const h4*)(Xh2 + (size_t)(i0 + 16 * t + l16) * DIM + quad * 4);
      ad[t] = *(const h4*)(Dh  + (size_t)(i0 + 16 * t + l16) * DIM + quad * 4);
      cif[t] = *(const float4*)(csq2 + i0 + 16 * t + quad * 4);
    }

    float s = 0.f;
    const int jbeg = bj * 256 + half * 128;
    const int jend = jbeg + 128;
#pragma unroll 4
    for (int j0 = jbeg; j0 < jend; j0 += 16) {
      const h4 bx = *(const h4*)(Xh2 + (size_t)(j0 + l16) * DIM + quad * 4);
      const h4 bd = *(const h4*)(Dh  + (size_t)(j0 + l16) * DIM + quad * 4);
      const float cj = csq2[j0 + l16];
#pragma unroll
      for (int t = 0; t < 4; ++t) {
        const f4 cc = {cif[t].x + cj, cif[t].y + cj, cif[t].z + cj, cif[t].w + cj};
        const f4 dx = MFMA16(ax[t], bx, cc);
        const f4 dd = MFMA16(ad[t], bd, fz);
#pragma unroll
        for (int r = 0; r < 4; ++r) s = fmaf(EXP2(dx[r]), dd[r], s);
      }
    }

    const float stot = block_sum(s * weight, wred);
    if (threadIdx.x == 0) unsafeAtomicAdd(&accums[0], stot);
  }

  __threadfence();
  if (threadIdx.x == 0) {
    unsigned* cnt = (unsigned*)&accums[2];
    const unsigned old = atomicAdd(cnt, 1u);
    if (old == gridDim.x * gridDim.y - 1) {
      const float a0 = __hip_atomic_load(&accums[0], __ATOMIC_ACQUIRE,
                                         __HIP_MEMORY_SCOPE_AGENT);
      const float a1 = __hip_atomic_load(&accums[1], __ATOMIC_ACQUIRE,
                                         __HIP_MEMORY_SCOPE_AGENT);
      out[0] = a0 + REG_LAMBDA * a1;
    }
  }
}

extern "C" void kernel_launch(void* const* d_in, const int* in_sizes, int n_in,
                              void* d_out, int out_size, void* d_ws, size_t ws_size,
                              hipStream_t stream) {
  const float4* Xv = (const float4*)d_in[0];
  const float4* Yv = (const float4*)d_in[1];
  const float4* Lv = (const float4*)d_in[2];
  float* out = (float*)d_out;

  // ws layout (bytes): Xh1 256K | Xh2 256K | LamT 256K | Dh 256K |
  //                    csq1 32K | csq2 32K | accums 256B | Upart jc*256K (fp16)
  char* base = (char*)d_ws;
  _Float16* Xh1  = (_Float16*)(base);
  _Float16* Xh2  = (_Float16*)(base + 256 * 1024);
  _Float16* LamT = (_Float16*)(base + 512 * 1024);
  _Float16* Dh   = (_Float16*)(base + 768 * 1024);
  float*    csq1 = (float*)(base + 1024 * 1024);
  float*    csq2 = (float*)(base + 1056 * 1024);
  float*    accums = (float*)(base + 1088 * 1024);
  _Float16* Upart  = (_Float16*)(base + 1088 * 1024 + 256);
  const size_t fixed = 1088 * 1024 + 256;

  int jc = 32;
  while (jc > 1 && fixed + (size_t)jc * NPTS * DIM * 2 > ws_size) jc >>= 1;
  const int span1 = NPTS / jc;

  k_prep<<<NIB, BLK, 0, stream>>>(Xv, Lv, Xh1, Xh2, LamT, csq1, csq2, accums);
  k_pass1<<<dim3(NPTS / 256, jc), BLK, 0, stream>>>(Xh1, LamT, csq1, Upart, span1);
  k_reduce<<<NPTS * 4 / BLK, BLK, 0, stream>>>(Upart, Yv, Lv, Dh, accums, jc);
  k_pass2<<<dim3(32, 34), BLK, 0, stream>>>(Xh2, Dh, csq2, accums, out);
}

// Round 14
// 113.263 us; speedup vs baseline: 1.5974x; 1.5974x over previous
//
#include <hip/hip_runtime.h>

// N=8192, D=16 RBF transport loss — all-MFMA, no-LDS (R12 structure).
// P^T via operand-swapped 16x16x16 MFMA; C/D layout == A-operand layout, so
// exp(P^T) feeds the second MFMA directly. RBF bias rides in the MFMA C
// operand (must stay pre-exp: removing it overflows fp16); exp() is raw
// v_exp_f32 via sqrt(log2e) pre-scaling.
// R14 = R12 + fp16 Upart. NOTE: do NOT fuse k_final into pass2 — the
// if(active){hot loop} + epilogue-tail structure makes the compiler allocate
// 164 VGPRs and 10x the kernel (R11/R13 evidence).
#define NPTS 8192
#define DIM  16

constexpr int BLK = 256;
constexpr int NIB = NPTS / BLK;   // 32

#define REG_LAMBDA 0.01f
#define C1 1.2011224087864498f   // sqrt(log2e)      -> exp(-d2/2)
#define C2 0.6005612043932249f   // 0.5*sqrt(log2e)  -> exp(-d2/8)

typedef _Float16 h4 __attribute__((ext_vector_type(4)));
typedef float    f4 __attribute__((ext_vector_type(4)));

#define MFMA16(a, b, c) __builtin_amdgcn_mfma_f32_16x16x16f16((a), (b), (c), 0, 0, 0)

#if __has_builtin(__builtin_amdgcn_exp2f)
#define EXP2(x) __builtin_amdgcn_exp2f(x)
#else
#define EXP2(x) exp2f(x)
#endif

__device__ __forceinline__ float dot4(float4 a, float4 b) {
  return fmaf(a.x, b.x, fmaf(a.y, b.y, fmaf(a.z, b.z, a.w * b.w)));
}

__device__ __forceinline__ float block_sum(float v, float* wbuf) {
#pragma unroll
  for (int o = 32; o > 0; o >>= 1) v += __shfl_down(v, o, 64);
  const int lane = threadIdx.x & 63;
  const int wid  = threadIdx.x >> 6;
  __syncthreads();
  if (lane == 0) wbuf[wid] = v;
  __syncthreads();
  float s = 0.f;
  if (threadIdx.x == 0) {
#pragma unroll
    for (int w = 0; w < BLK / 64; ++w) s += wbuf[w];
  }
  return s;
}

// Prep: two pre-scaled fp16 X copies, LamT (16 x N, fp16), csq from ROUNDED X.
// Also zeroes the accumulators (ws is poisoned 0xAA before every call).
__global__ __launch_bounds__(BLK) void k_prep(
    const float4* __restrict__ Xv, const float4* __restrict__ Lv,
    _Float16* __restrict__ Xh1, _Float16* __restrict__ Xh2,
    _Float16* __restrict__ LamT,
    float* __restrict__ csq1, float* __restrict__ csq2,
    float* __restrict__ accums) {
  if (blockIdx.x == 0 && threadIdx.x < 4) accums[threadIdx.x] = 0.f;
  const int i = blockIdx.x * BLK + threadIdx.x;
  float sq1 = 0.f, sq2 = 0.f;
  h4* x1 = (h4*)(Xh1 + (size_t)i * DIM);
  h4* x2 = (h4*)(Xh2 + (size_t)i * DIM);
#pragma unroll
  for (int q = 0; q < 4; ++q) {
    const float4 v = Xv[(size_t)i * 4 + q];
    h4 a = {(_Float16)(C1 * v.x), (_Float16)(C1 * v.y),
            (_Float16)(C1 * v.z), (_Float16)(C1 * v.w)};
    h4 b = {(_Float16)(C2 * v.x), (_Float16)(C2 * v.y),
            (_Float16)(C2 * v.z), (_Float16)(C2 * v.w)};
    x1[q] = a; x2[q] = b;
#pragma unroll
    for (int t = 0; t < 4; ++t) {
      const float fa = (float)a[t], fb = (float)b[t];
      sq1 = fmaf(fa, fa, sq1);
      sq2 = fmaf(fb, fb, sq2);
    }
    const float4 l = Lv[(size_t)i * 4 + q];
    LamT[(size_t)(4 * q + 0) * NPTS + i] = (_Float16)l.x;
    LamT[(size_t)(4 * q + 1) * NPTS + i] = (_Float16)l.y;
    LamT[(size_t)(4 * q + 2) * NPTS + i] = (_Float16)l.z;
    LamT[(size_t)(4 * q + 3) * NPTS + i] = (_Float16)l.w;
  }
  csq1[i] = -0.5f * sq1;
  csq2[i] = -0.5f * sq2;
}

// Pass 1 (R8): U = exp2(Xj.Xi^T + bias) @ Lam. 4 i-tiles per wave,
// 256 i per block, grid (32, 32). Partials stored fp16.
__global__ __launch_bounds__(BLK) void k_pass1(
    const _Float16* __restrict__ Xh1, const _Float16* __restrict__ LamT,
    const float* __restrict__ csq1, _Float16* __restrict__ Upart, int span) {
  const int lane = threadIdx.x & 63;
  const int w    = threadIdx.x >> 6;
  const int l16  = lane & 15;
  const int quad = lane >> 4;

  const int i0 = blockIdx.x * 256 + w * 64;   // tiles i0+16t, t=0..3
  h4 bxi[4];
  float ci[4];
#pragma unroll
  for (int t = 0; t < 4; ++t) {
    bxi[t] = *(const h4*)(Xh1 + (size_t)(i0 + 16 * t + l16) * DIM + quad * 4);
    ci[t]  = csq1[i0 + 16 * t + l16];
  }
  const _Float16* blrow = LamT + (size_t)l16 * NPTS;

  f4 U[4] = {{0.f, 0.f, 0.f, 0.f}, {0.f, 0.f, 0.f, 0.f},
             {0.f, 0.f, 0.f, 0.f}, {0.f, 0.f, 0.f, 0.f}};
  const int jbeg = blockIdx.y * span;
  const int jend = jbeg + span;
#pragma unroll 4
  for (int j0 = jbeg; j0 < jend; j0 += 16) {
    const h4 axj = *(const h4*)(Xh1 + (size_t)(j0 + l16) * DIM + quad * 4);
    const float4 cjf = *(const float4*)(csq1 + j0 + quad * 4);
    const h4 bl = *(const h4*)(blrow + j0 + quad * 4);
#pragma unroll
    for (int t = 0; t < 4; ++t) {
      const f4 cc = {cjf.x + ci[t], cjf.y + ci[t], cjf.z + ci[t], cjf.w + ci[t]};
      const f4 p = MFMA16(axj, bxi[t], cc);   // P^T tile t (+bias)
      h4 ap;
#pragma unroll
      for (int r = 0; r < 4; ++r) ap[r] = (_Float16)EXP2(p[r]);
      U[t] = MFMA16(ap, bl, U[t]);
    }
  }

  _Float16* dst = Upart + ((size_t)blockIdx.y * NPTS + i0) * DIM;
#pragma unroll
  for (int t = 0; t < 4; ++t)
#pragma unroll
    for (int r = 0; r < 4; ++r)
      dst[(16 * t + quad * 4 + r) * DIM + l16] = (_Float16)U[t][r];
}

// Reduce fp16 partials -> diff = U - Y (fp16 Dh); reg = sum(Lam * U).
__global__ __launch_bounds__(BLK) void k_reduce(
    const _Float16* __restrict__ Upart, const float4* __restrict__ Yv,
    const float4* __restrict__ Lv, _Float16* __restrict__ Dh,
    float* __restrict__ accums, int jc) {
  __shared__ float wred[BLK / 64];
  const int t = blockIdx.x * BLK + threadIdx.x;
  const int i = t >> 2, q = t & 3;
  float4 u = {0.f, 0.f, 0.f, 0.f};
  for (int c = 0; c < jc; ++c) {
    const h4 p = *(const h4*)(Upart + ((size_t)c * NPTS + i) * DIM + q * 4);
    u.x += (float)p[0]; u.y += (float)p[1];
    u.z += (float)p[2]; u.w += (float)p[3];
  }
  const float4 y = Yv[(size_t)i * 4 + q];
  h4 d = {(_Float16)(u.x - y.x), (_Float16)(u.y - y.y),
          (_Float16)(u.z - y.z), (_Float16)(u.w - y.w)};
  *(h4*)(Dh + (size_t)i * DIM + q * 4) = d;
  const float regp = dot4(Lv[(size_t)i * 4 + q], u);
  const float rtot = block_sum(regp, wred);
  if (threadIdx.x == 0) unsafeAtomicAdd(&accums[1], rtot);
}

// Pass 2, symmetric: wrapped-triangle block map, early-return inactive blocks
// (NO epilogue tail — see R11/R13 note above). k=0 weight 1, else 2;
// k==16 only bi<16.
__global__ __launch_bounds__(BLK) void k_pass2(
    const _Float16* __restrict__ Xh2, const _Float16* __restrict__ Dh,
    const float* __restrict__ csq2, float* __restrict__ accums) {
  __shared__ float wred[BLK / 64];
  const int bi   = blockIdx.x;
  const int k    = blockIdx.y >> 1;
  const int half = blockIdx.y & 1;
  if (k == 16 && bi >= 16) return;   // block-uniform exit
  const int bj = (bi + k) & 31;
  const float weight = (k == 0) ? 1.f : 2.f;

  const int lane = threadIdx.x & 63;
  const int w    = threadIdx.x >> 6;
  const int l16  = lane & 15;
  const int quad = lane >> 4;
  const f4 fz = {0.f, 0.f, 0.f, 0.f};

  const int i0 = bi * 256 + w * 64;
  h4 ax[4], ad[4];
  float4 cif[4];
#pragma unroll
  for (int t = 0; t < 4; ++t) {
    ax[t] = *(const h4*)(Xh2 + (size_t)(i0 + 16 * t + l16) * DIM + quad * 4);
    ad[t] = *(const h4*)(Dh  + (size_t)(i0 + 16 * t + l16) * DIM + quad * 4);
    cif[t] = *(const float4*)(csq2 + i0 + 16 * t + quad * 4);
  }

  float s = 0.f;
  const int jbeg = bj * 256 + half * 128;
  const int jend = jbeg + 128;
#pragma unroll 4
  for (int j0 = jbeg; j0 < jend; j0 += 16) {
    const h4 bx = *(const h4*)(Xh2 + (size_t)(j0 + l16) * DIM + quad * 4);
    const h4 bd = *(const h4*)(Dh  + (size_t)(j0 + l16) * DIM + quad * 4);
    const float cj = csq2[j0 + l16];
#pragma unroll
    for (int t = 0; t < 4; ++t) {
      const f4 cc = {cif[t].x + cj, cif[t].y + cj, cif[t].z + cj, cif[t].w + cj};
      const f4 dx = MFMA16(ax[t], bx, cc);
      const f4 dd = MFMA16(ad[t], bd, fz);
#pragma unroll
      for (int r = 0; r < 4; ++r) s = fmaf(EXP2(dx[r]), dd[r], s);
    }
  }

  const float stot = block_sum(s * weight, wred);
  if (threadIdx.x == 0) unsafeAtomicAdd(&accums[0], stot);
}

__global__ void k_final(const float* __restrict__ accums, float* __restrict__ out) {
  out[0] = accums[0] + REG_LAMBDA * accums[1];
}

extern "C" void kernel_launch(void* const* d_in, const int* in_sizes, int n_in,
                              void* d_out, int out_size, void* d_ws, size_t ws_size,
                              hipStream_t stream) {
  const float4* Xv = (const float4*)d_in[0];
  const float4* Yv = (const float4*)d_in[1];
  const float4* Lv = (const float4*)d_in[2];
  float* out = (float*)d_out;

  // ws layout (bytes): Xh1 256K | Xh2 256K | LamT 256K | Dh 256K |
  //                    csq1 32K | csq2 32K | accums 256B | Upart jc*256K (fp16)
  char* base = (char*)d_ws;
  _Float16* Xh1  = (_Float16*)(base);
  _Float16* Xh2  = (_Float16*)(base + 256 * 1024);
  _Float16* LamT = (_Float16*)(base + 512 * 1024);
  _Float16* Dh   = (_Float16*)(base + 768 * 1024);
  float*    csq1 = (float*)(base + 1024 * 1024);
  float*    csq2 = (float*)(base + 1056 * 1024);
  float*    accums = (float*)(base + 1088 * 1024);
  _Float16* Upart  = (_Float16*)(base + 1088 * 1024 + 256);
  const size_t fixed = 1088 * 1024 + 256;

  int jc = 32;
  while (jc > 1 && fixed + (size_t)jc * NPTS * DIM * 2 > ws_size) jc >>= 1;
  const int span1 = NPTS / jc;

  k_prep<<<NIB, BLK, 0, stream>>>(Xv, Lv, Xh1, Xh2, LamT, csq1, csq2, accums);
  k_pass1<<<dim3(NPTS / 256, jc), BLK, 0, stream>>>(Xh1, LamT, csq1, Upart, span1);
  k_reduce<<<NPTS * 4 / BLK, BLK, 0, stream>>>(Upart, Yv, Lv, Dh, accums, jc);
  k_pass2<<<dim3(32, 34), BLK, 0, stream>>>(Xh2, Dh, csq2, accums);
  k_final<<<1, 1, 0, stream>>>(accums, out);
}